// Round 10
// baseline (2732.099 us; speedup 1.0000x reference)
//
#include <hip/hip_runtime.h>
#include <math.h>

#define NN 1024           // N (logical)
#define LD 1040           // padded leading dimension (kept from r9; neutral)
#define NB 64             // panel width
#define TB 128            // tail handled by tailsyrk+finish
#define CROSS (NN - TB)   // 896: panel loop covers p < CROSS
#define NSAMP 64          // n_mc

#define CCONST  (-0.91893853320467274f)   // -0.5*log(2*pi)
#define LOG2PI  (1.8378770664093453f)

__device__ __forceinline__ float bcastf(float v, int lane) {
    return __int_as_float(__builtin_amdgcn_readlane(__float_as_int(v), lane));
}
__device__ __forceinline__ float softplus_d(float v) {
    return (v > 20.f ? v : log1pf(expf(v))) + 1e-7f;
}
__device__ __forceinline__ float log_normal_f(float v, float mean, float s, float eps) {
    float d = v - mean;
    return -d * d / (2.f * s * s + eps) - logf(s) + CCONST;
}
__device__ __forceinline__ float log_lognormal_f(float v, float mean, float s) {
    float lv = logf(v);
    float d = lv - mean;
    return -d * d / (2.f * s * s + 1e-6f) - lv - logf(s) + CCONST;
}
__device__ __forceinline__ void fma4(float4& c, float a, const float4& b) {
    c.x = fmaf(a, b.x, c.x); c.y = fmaf(a, b.y, c.y);
    c.z = fmaf(a, b.z, c.z); c.w = fmaf(a, b.w, c.w);
}

// ---------------- per-sample scalars ----------------
__global__ void scal_kernel(const float* __restrict__ z,
    const float* qbm, const float* qbs, const float* qsm, const float* qss,
    const float* qem, const float* qes, const float* qzm, const float* qzs,
    const float* qnm, const float* qns, float* __restrict__ scal)
{
    int m = threadIdx.x;
    if (m >= NSAMP) return;
    float z0 = z[m*5+0], z1 = z[m*5+1], z2 = z[m*5+2], z3 = z[m*5+3], z4 = z[m*5+4];
    float spb = softplus_d(qbs[0]);
    float sps = softplus_d(qss[0]);
    float spe = softplus_d(qes[0]);
    float spz = softplus_d(qzs[0]);
    float spn = softplus_d(qns[0]);
    float sigma2 = expf(z0 * sps + qsm[0]);
    float beta   = z1 * spb + qbm[0];
    float eta    = expf(z2 * spe + qem[0]);
    float lsZ    = expf(z3 * spz + qzm[0]);
    float lsN    = expf(z4 * spn + qnm[0]);
    float s0 = softplus_d(sqrtf(logf(2.f)));
    float lp = log_normal_f(beta, 0.f, 1.f, 1e-5f)
             + log_lognormal_f(sigma2, 1.f, s0)
             + log_lognormal_f(eta,    1.f, s0)
             + log_lognormal_f(lsZ,    1.f, s0)
             + log_lognormal_f(lsN,    1.f, s0);
    float lq = log_normal_f(beta, qbm[0], spb, 1e-5f)
             + log_lognormal_f(sigma2, qsm[0], sps)
             + log_lognormal_f(eta,    qem[0], spe)
             + log_lognormal_f(lsZ,    qzm[0], spz)
             + log_lognormal_f(lsN,    qnm[0], spn);
    scal[m]           = sigma2;
    scal[NSAMP + m]   = eta;
    scal[2*NSAMP + m] = 1.f / lsZ;
    scal[3*NSAMP + m] = 1.f / lsN;
    scal[4*NSAMP + m] = beta;
    scal[5*NSAMP + m] = lp - lq;
}

// ---------------- covariance build (lower triangle) + bvec/stats init ----------------
__global__ __launch_bounds__(256)
void cov_kernel(float* __restrict__ cov, const float* __restrict__ scal,
                const float* __restrict__ x, const float* __restrict__ y,
                float* __restrict__ bvec, float* __restrict__ stats, int mbase)
{
    int i  = blockIdx.x;
    int ml = blockIdx.y;
    int m  = mbase + ml;
    if (threadIdx.x == 0) {
        bvec[(size_t)m * NN + i] = y[i] - scal[4*NSAMP + m];
        if (i == 0) { stats[2*m] = 0.f; stats[2*m+1] = 0.f; }
    }
    float sigma2 = scal[m];
    float eta    = scal[NSAMP + m];
    float ilZ    = scal[2*NSAMP + m];
    float ilN    = scal[3*NSAMP + m];
    float xi0 = x[2*i]   * ilZ;
    float xi1 = x[2*i+1] * ilN;
    float* row = cov + (size_t)ml * NN * LD + (size_t)i * LD;
    int j0 = threadIdx.x * 4;
    if (j0 > i) return;
    float4 xa = *(const float4*)(x + 2*j0);
    float4 xb = *(const float4*)(x + 2*j0 + 4);
    float v[4]; float d0, d1;
    d0 = xa.x*ilZ - xi0; d1 = xa.y*ilN - xi1; v[0] = eta*__expf(-0.5f*(d0*d0+d1*d1));
    d0 = xa.z*ilZ - xi0; d1 = xa.w*ilN - xi1; v[1] = eta*__expf(-0.5f*(d0*d0+d1*d1));
    d0 = xb.x*ilZ - xi0; d1 = xb.y*ilN - xi1; v[2] = eta*__expf(-0.5f*(d0*d0+d1*d1));
    d0 = xb.z*ilZ - xi0; d1 = xb.w*ilN - xi1; v[3] = eta*__expf(-0.5f*(d0*d0+d1*d1));
    #pragma unroll
    for (int q = 0; q < 4; ++q) if (j0 + q == i) v[q] += sigma2;
    if (j0 + 3 <= i) {
        float4 o; o.x = v[0]; o.y = v[1]; o.z = v[2]; o.w = v[3];
        *(float4*)(row + j0) = o;
    } else {
        #pragma unroll
        for (int q = 0; q < 4; ++q) if (j0 + q <= i) row[j0+q] = v[q];
    }
}

// ---------------- left-looking block-column update (GEMM, K = p) ----------------
__global__ __launch_bounds__(256)
void update_kernel(float* __restrict__ covb, int p)
{
    int ml = blockIdx.y;
    float* C = covb + (size_t)ml * NN * LD;
    int rowbase = p + blockIdx.x * 128;

    __shared__ __align__(16) float As[32][132];  // k-major, 128 rows
    __shared__ __align__(16) float Bs[32][68];   // k-major, 64 rows

    int tid = threadIdx.x;
    int tx = tid & 7,  ty = tid >> 3;
    int c0 = tx * 8,   r0 = ty * 4;

    float4 acc[4][2];
    #pragma unroll
    for (int r = 0; r < 4; ++r) { acc[r][0] = make_float4(0,0,0,0); acc[r][1] = make_float4(0,0,0,0); }

    for (int ks = 0; ks < p; ks += 32) {
        for (int idx = tid; idx < 128 * 8; idx += 256) {
            int ii = idx >> 3;
            int c4 = (idx & 7) << 2;
            int gr = rowbase + ii;
            float4 v = make_float4(0,0,0,0);
            if (gr < NN) v = *(const float4*)(C + (size_t)gr * LD + ks + c4);
            As[c4+0][ii] = v.x; As[c4+1][ii] = v.y;
            As[c4+2][ii] = v.z; As[c4+3][ii] = v.w;
        }
        for (int idx = tid; idx < 64 * 8; idx += 256) {
            int ii = idx >> 3;
            int c4 = (idx & 7) << 2;
            float4 v = *(const float4*)(C + (size_t)(p + ii) * LD + ks + c4);
            Bs[c4+0][ii] = v.x; Bs[c4+1][ii] = v.y;
            Bs[c4+2][ii] = v.z; Bs[c4+3][ii] = v.w;
        }
        __syncthreads();
        #pragma unroll
        for (int k = 0; k < 32; ++k) {
            float4 b0 = *(const float4*)&Bs[k][c0];
            float4 b1 = *(const float4*)&Bs[k][c0 + 4];
            float4 a0 = *(const float4*)&As[k][r0];
            float ar[4] = {a0.x, a0.y, a0.z, a0.w};
            #pragma unroll
            for (int r = 0; r < 4; ++r) {
                fma4(acc[r][0], ar[r], b0);
                fma4(acc[r][1], ar[r], b1);
            }
        }
        __syncthreads();
    }

    int jcol = p + c0;
    #pragma unroll
    for (int r = 0; r < 4; ++r) {
        int g = rowbase + r0 + r;
        if (g < NN) {
            float* cp = C + (size_t)g * LD + jcol;
            float4 u0 = *(float4*)cp;
            float4 u1 = *((float4*)cp + 1);
            u0.x -= acc[r][0].x; u0.y -= acc[r][0].y; u0.z -= acc[r][0].z; u0.w -= acc[r][0].w;
            u1.x -= acc[r][1].x; u1.y -= acc[r][1].y; u1.z -= acc[r][1].z; u1.w -= acc[r][1].w;
            *(float4*)cp = u0;
            *((float4*)cp + 1) = u1;
        }
    }
}

// ---------------- small-tile update for late panels (rt*mc starved) ----------------
__global__ __launch_bounds__(256)
void update_small_kernel(float* __restrict__ covb, int p)
{
    int ml = blockIdx.y;
    float* C = covb + (size_t)ml * NN * LD;
    int rowbase = p + blockIdx.x * 64;
    int zoff = blockIdx.z * 32;

    __shared__ __align__(16) float As[32][68];   // k-major, 64 rows
    __shared__ __align__(16) float Bs[32][36];   // k-major, 32 rows

    int tid = threadIdx.x;
    int tx = tid & 7,  ty = tid >> 3;   // 8 col-quads x 32 row-pairs
    int c0 = tx * 4,   r0 = ty * 2;

    float4 acc0 = make_float4(0,0,0,0), acc1 = make_float4(0,0,0,0);

    for (int ks = 0; ks < p; ks += 32) {
        for (int idx = tid; idx < 64 * 8; idx += 256) {
            int ii = idx >> 3;
            int c4 = (idx & 7) << 2;
            int gr = rowbase + ii;
            float4 v = make_float4(0,0,0,0);
            if (gr < NN) v = *(const float4*)(C + (size_t)gr * LD + ks + c4);
            As[c4+0][ii] = v.x; As[c4+1][ii] = v.y;
            As[c4+2][ii] = v.z; As[c4+3][ii] = v.w;
        }
        {
            int idx = tid;                      // 32*8 = 256 exactly
            int ii = idx >> 3;
            int c4 = (idx & 7) << 2;
            float4 v = *(const float4*)(C + (size_t)(p + zoff + ii) * LD + ks + c4);
            Bs[c4+0][ii] = v.x; Bs[c4+1][ii] = v.y;
            Bs[c4+2][ii] = v.z; Bs[c4+3][ii] = v.w;
        }
        __syncthreads();
        #pragma unroll
        for (int k = 0; k < 32; ++k) {
            float4 bv = *(const float4*)&Bs[k][c0];
            float2 av = *(const float2*)&As[k][r0];
            fma4(acc0, av.x, bv);
            fma4(acc1, av.y, bv);
        }
        __syncthreads();
    }

    int jcol = p + zoff + c0;
    int g0 = rowbase + r0;
    if (g0 < NN) {
        float* cp = C + (size_t)g0 * LD + jcol;
        float4 u = *(float4*)cp;
        u.x -= acc0.x; u.y -= acc0.y; u.z -= acc0.z; u.w -= acc0.w;
        *(float4*)cp = u;
    }
    if (g0 + 1 < NN) {
        float* cp = C + (size_t)(g0 + 1) * LD + jcol;
        float4 u = *(float4*)cp;
        u.x -= acc1.x; u.y -= acc1.y; u.z -= acc1.z; u.w -= acc1.w;
        *(float4*)cp = u;
    }
}

// ---------------- fused diag factor + panel TRSM + forward solve ----------------
// r10: 128 threads (wave 0 = redundant in-register diag factor; wave 1 = 64
// TRSM rows), grid (rb/64, mc) -> ~8x blocks vs r9 (latency hiding), and the
// TRSM inner product uses 4 split accumulators to cut the dependent-FMA chain.
__global__ __launch_bounds__(128)
void trsmdiag_kernel(float* __restrict__ covb, float* __restrict__ bvec,
                     float* __restrict__ stats, const float* __restrict__ scal,
                     int mbase, int p)
{
    int ml = blockIdx.y;
    int m  = mbase + ml;
    float* C = covb + (size_t)ml * NN * LD;
    __shared__ __align__(16) float Tl[NB][68];
    __shared__ float rs_s[NB], sol_s[NB];
    int tid = threadIdx.x;

    // wave 1: pre-load TRSM row (issued before the factor stalls on it)
    int r0 = p + NB + blockIdx.x * 64 + (tid - 64);
    bool have = (tid >= 64);
    float l[NB];
    if (have) {
        const float* rowp = C + (size_t)r0 * LD + p;
        #pragma unroll
        for (int q = 0; q < NB/4; ++q) {
            float4 v = *(const float4*)(rowp + 4*q);
            l[4*q] = v.x; l[4*q+1] = v.y; l[4*q+2] = v.z; l[4*q+3] = v.w;
        }
    }

    // wave 0: in-register diag factor + forward solve
    if (tid < 64) {
        int r = tid;
        float row[NB];
        const float* src = C + (size_t)(p + r) * LD + p;
        #pragma unroll
        for (int q = 0; q < NB/4; ++q) {
            float4 v = *(const float4*)(src + 4*q);
            row[4*q+0] = v.x; row[4*q+1] = v.y; row[4*q+2] = v.z; row[4*q+3] = v.w;
        }
        float b = bvec[(size_t)m * NN + p + r];
        float quad_add = 0.f, my_d = 1.f;
        #pragma unroll
        for (int j = 0; j < NB; ++j) {
            float dj = fmaxf(bcastf(row[j], j), 1e-30f);
            float rs = rsqrtf(dj);
            if (r == j) my_d = dj;
            row[j] *= rs;
            float sj = bcastf(b, j) * rs;
            quad_add = fmaf(sj, sj, quad_add);
            b = fmaf(-row[j], sj, b);
            if (r == j) { rs_s[j] = rs; sol_s[j] = sj; }
            #pragma unroll
            for (int c = j + 1; c < NB; ++c) {
                float s = bcastf(row[j], c);
                row[c] = fmaf(-row[j], s, row[c]);
            }
        }
        #pragma unroll
        for (int q = 0; q < NB/4; ++q) {
            float4 v; v.x = row[4*q]; v.y = row[4*q+1]; v.z = row[4*q+2]; v.w = row[4*q+3];
            *(float4*)&Tl[r][4*q] = v;
        }
        if (blockIdx.x == 0) {
            float ldv = logf(my_d);
            #pragma unroll
            for (int off = 32; off > 0; off >>= 1) ldv += __shfl_down(ldv, off);
            if (r == 0) {
                stats[2*m]   += quad_add;
                stats[2*m+1] += ldv;
            }
        }
    }
    __syncthreads();

    if (!have) return;
    float* rowp = C + (size_t)r0 * LD + p;
    #pragma unroll
    for (int j = 0; j < NB; ++j) {
        // 4 split accumulators: dependent chain j -> j/4
        float s0 = l[j], s1 = 0.f, s2 = 0.f, s3 = 0.f;
        int c = 0;
        #pragma unroll
        for (; c + 4 <= j; c += 4) {
            float4 t = *(const float4*)&Tl[j][c];
            s0 = fmaf(-l[c],   t.x, s0);
            s1 = fmaf(-l[c+1], t.y, s1);
            s2 = fmaf(-l[c+2], t.z, s2);
            s3 = fmaf(-l[c+3], t.w, s3);
        }
        #pragma unroll
        for (; c < j; ++c) s0 = fmaf(-l[c], Tl[j][c], s0);
        l[j] = ((s0 + s1) + (s2 + s3)) * rs_s[j];
    }
    #pragma unroll
    for (int q = 0; q < NB/4; ++q) {
        float4 v; v.x = l[4*q]; v.y = l[4*q+1]; v.z = l[4*q+2]; v.w = l[4*q+3];
        *(float4*)(rowp + 4*q) = v;
    }
    float b0 = 0.f, b1 = 0.f, b2 = 0.f, b3 = 0.f;
    #pragma unroll
    for (int j = 0; j < NB; j += 4) {
        b0 = fmaf(l[j],   sol_s[j],   b0);
        b1 = fmaf(l[j+1], sol_s[j+1], b1);
        b2 = fmaf(l[j+2], sol_s[j+2], b2);
        b3 = fmaf(l[j+3], sol_s[j+3], b3);
    }
    bvec[(size_t)m * NN + r0] -= ((b0 + b1) + (b2 + b3));
}

// ---------------- tail SYRK, split-K partials ----------------
// partial_z stored to the unused strictly-upper region: rows 0..127,
// cols 512 + z*128 .. +128 (never touched by the lower-triangle pipeline).
__global__ __launch_bounds__(256)
void tailsyrk_kernel(float* __restrict__ covb)
{
    int ml = blockIdx.y;
    float* C = covb + (size_t)ml * NN * LD;
    int z  = blockIdx.x;
    int k0 = z * (CROSS / 4);            // 224 per segment

    __shared__ __align__(16) float As[32][132];
    int tid = threadIdx.x;
    int tx = tid & 15, ty = tid >> 4;
    int c0 = tx * 8, r0 = ty * 8;

    float4 acc[8][2];
    #pragma unroll
    for (int r = 0; r < 8; ++r) { acc[r][0] = make_float4(0,0,0,0); acc[r][1] = make_float4(0,0,0,0); }

    for (int ks = k0; ks < k0 + CROSS/4; ks += 32) {
        for (int idx = tid; idx < 128 * 8; idx += 256) {
            int ii = idx >> 3;
            int c4 = (idx & 7) << 2;
            float4 v = *(const float4*)(C + (size_t)(CROSS + ii) * LD + ks + c4);
            As[c4+0][ii] = v.x; As[c4+1][ii] = v.y;
            As[c4+2][ii] = v.z; As[c4+3][ii] = v.w;
        }
        __syncthreads();
        #pragma unroll
        for (int k = 0; k < 32; ++k) {
            float4 b0 = *(const float4*)&As[k][c0];
            float4 b1 = *(const float4*)&As[k][c0 + 4];
            float4 a0 = *(const float4*)&As[k][r0];
            float4 a1 = *(const float4*)&As[k][r0 + 4];
            float ar[8] = {a0.x, a0.y, a0.z, a0.w, a1.x, a1.y, a1.z, a1.w};
            #pragma unroll
            for (int r = 0; r < 8; ++r) {
                fma4(acc[r][0], ar[r], b0);
                fma4(acc[r][1], ar[r], b1);
            }
        }
        __syncthreads();
    }

    #pragma unroll
    for (int r = 0; r < 8; ++r) {
        float* cp = C + (size_t)(r0 + r) * LD + 512 + z * 128 + c0;
        *(float4*)cp = acc[r][0];
        *((float4*)cp + 1) = acc[r][1];
    }
}

// ---------------- reduce the 4 tail partials into C[896:,896:] ----------------
__global__ __launch_bounds__(256)
void tailreduce_kernel(float* __restrict__ covb)
{
    int ml = blockIdx.x;
    float* C = covb + (size_t)ml * NN * LD;
    int tid = threadIdx.x;
    for (int f = tid; f < 128 * 32; f += 256) {     // float4 units
        int i  = f >> 5;
        int c4 = (f & 31) << 2;
        float4 s = make_float4(0,0,0,0);
        #pragma unroll
        for (int z = 0; z < 4; ++z) {
            float4 v = *(const float4*)(C + (size_t)i * LD + 512 + z * 128 + c4);
            s.x += v.x; s.y += v.y; s.z += v.z; s.w += v.w;
        }
        float* cp = C + (size_t)(CROSS + i) * LD + CROSS + c4;
        float4 u = *(float4*)cp;
        u.x -= s.x; u.y -= s.y; u.z -= s.z; u.w -= s.w;
        *(float4*)cp = u;
    }
}

// ---------------- per-sample finish: factor last 128x128 + solve + output ----------------
__global__ __launch_bounds__(256)
void finish_kernel(float* __restrict__ covb, const float* __restrict__ bvec,
                   const float* __restrict__ stats, float* __restrict__ out,
                   const float* __restrict__ scal, int mbase)
{
    int ml = blockIdx.x;
    int m  = mbase + ml;
    float* C = covb + (size_t)ml * NN * LD;
    __shared__ __align__(16) float Tl[NB][68];
    __shared__ float rs_s[NB], sol_s[NB];
    __shared__ float bt[TB];
    __shared__ __align__(16) float Ps[NB][72];   // k-major TRSM panel (rows <= 64)
    __shared__ float s_quad, s_ld;
    int tid = threadIdx.x;

    for (int r = tid; r < TB; r += 256) bt[r] = bvec[(size_t)m * NN + CROSS + r];
    if (tid == 0) { s_quad = 0.f; s_ld = 0.f; }
    __syncthreads();

    for (int sp = 0; sp < TB/NB; ++sp) {
        int pb = CROSS + sp * NB;
        int lb = sp * NB;
        int nrem = TB - lb - NB;

        if (tid < 64) {
            int r = tid;
            float row[NB];
            const float* src = C + (size_t)(pb + r) * LD + pb;
            #pragma unroll
            for (int q = 0; q < NB/4; ++q) {
                float4 v = *(const float4*)(src + 4*q);
                row[4*q+0] = v.x; row[4*q+1] = v.y; row[4*q+2] = v.z; row[4*q+3] = v.w;
            }
            float b = bt[lb + r];
            float quad_add = 0.f, my_d = 1.f;
            #pragma unroll
            for (int j = 0; j < NB; ++j) {
                float dj = fmaxf(bcastf(row[j], j), 1e-30f);
                float rs = rsqrtf(dj);
                if (r == j) my_d = dj;
                row[j] *= rs;
                float sj = bcastf(b, j) * rs;
                quad_add = fmaf(sj, sj, quad_add);
                b = fmaf(-row[j], sj, b);
                if (r == j) { rs_s[j] = rs; sol_s[j] = sj; }
                #pragma unroll
                for (int c = j + 1; c < NB; ++c) {
                    float s = bcastf(row[j], c);
                    row[c] = fmaf(-row[j], s, row[c]);
                }
            }
            #pragma unroll
            for (int q = 0; q < NB/4; ++q) {
                float4 v; v.x = row[4*q]; v.y = row[4*q+1]; v.z = row[4*q+2]; v.w = row[4*q+3];
                *(float4*)&Tl[r][4*q] = v;
            }
            float ldv = logf(my_d);
            #pragma unroll
            for (int off = 32; off > 0; off >>= 1) ldv += __shfl_down(ldv, off);
            if (r == 0) { s_quad += quad_add; s_ld += ldv; }
        }
        __syncthreads();

        if (nrem > 0) {
            int rr = tid - 64;
            if (tid >= 64 && rr < nrem) {
                int gr = pb + NB + rr;
                const float* rowp = C + (size_t)gr * LD + pb;
                float l[NB];
                #pragma unroll
                for (int q = 0; q < NB/4; ++q) {
                    float4 v = *(const float4*)(rowp + 4*q);
                    l[4*q] = v.x; l[4*q+1] = v.y; l[4*q+2] = v.z; l[4*q+3] = v.w;
                }
                #pragma unroll
                for (int j = 0; j < NB; ++j) {
                    float s0 = l[j], s1 = 0.f, s2 = 0.f, s3 = 0.f;
                    int c = 0;
                    #pragma unroll
                    for (; c + 4 <= j; c += 4) {
                        float4 t = *(const float4*)&Tl[j][c];
                        s0 = fmaf(-l[c],   t.x, s0);
                        s1 = fmaf(-l[c+1], t.y, s1);
                        s2 = fmaf(-l[c+2], t.z, s2);
                        s3 = fmaf(-l[c+3], t.w, s3);
                    }
                    #pragma unroll
                    for (; c < j; ++c) s0 = fmaf(-l[c], Tl[j][c], s0);
                    l[j] = ((s0 + s1) + (s2 + s3)) * rs_s[j];
                }
                #pragma unroll
                for (int k = 0; k < NB; ++k) Ps[k][rr] = l[k];
                float bacc = 0.f;
                #pragma unroll
                for (int j = 0; j < NB; ++j) bacc = fmaf(l[j], sol_s[j], bacc);
                bt[lb + NB + rr] -= bacc;
            }
            __syncthreads();

            int ng = nrem >> 2;
            for (int idx = tid; idx < nrem * ng; idx += 256) {
                int i  = idx / ng;
                int j4 = (idx - i * ng) << 2;
                if (j4 > i) continue;
                float4 a = make_float4(0,0,0,0);
                #pragma unroll 8
                for (int k = 0; k < NB; ++k) {
                    float4 pj = *(const float4*)&Ps[k][j4];
                    fma4(a, Ps[k][i], pj);
                }
                float* cp = C + (size_t)(pb + NB + i) * LD + (pb + NB + j4);
                float4 u = *(float4*)cp;
                u.x -= a.x; u.y -= a.y; u.z -= a.z; u.w -= a.w;
                *(float4*)cp = u;
            }
            __syncthreads();
        }
    }

    if (tid == 0) {
        float qt = stats[2*m]   + s_quad;
        float lt = stats[2*m+1] + s_ld;
        out[m] = -0.5f * (qt + lt + (float)NN * LOG2PI) + scal[5*NSAMP + m];
    }
}

extern "C" void kernel_launch(void* const* d_in, const int* in_sizes, int n_in,
                              void* d_out, int out_size, void* d_ws, size_t ws_size,
                              hipStream_t stream)
{
    const float* x   = (const float*)d_in[0];
    const float* y   = (const float*)d_in[1];
    const float* z   = (const float*)d_in[2];
    const float* qbm = (const float*)d_in[3];
    const float* qbs = (const float*)d_in[4];
    const float* qsm = (const float*)d_in[5];
    const float* qss = (const float*)d_in[6];
    const float* qem = (const float*)d_in[7];
    const float* qes = (const float*)d_in[8];
    const float* qzm = (const float*)d_in[9];
    const float* qzs = (const float*)d_in[10];
    const float* qnm = (const float*)d_in[11];
    const float* qns = (const float*)d_in[12];
    float* out  = (float*)d_out;
    float* ws   = (float*)d_ws;

    // workspace layout (floats)
    float* scal   = ws;                                   // 384 used
    float* bvec   = ws + 1024;                            // 64*1024
    float* stats  = ws + 1024 + NSAMP*NN;                 // 128 used, 512 res
    float* cov    = ws + 1024 + NSAMP*NN + 512;
    size_t headF  = 1024 + (size_t)NSAMP*NN + 512;

    scal_kernel<<<1, 64, 0, stream>>>(z, qbm, qbs, qsm, qss, qem, qes, qzm, qzs, qnm, qns, scal);

    size_t availF = ws_size / 4;
    size_t perM   = (size_t)NN * LD;       // padded per-matrix footprint
    int mc_max = NSAMP;
    if (availF < headF + (size_t)NSAMP * perM) {
        size_t rem = (availF > headF) ? (availF - headF) : 0;
        mc_max = (int)(rem / perM);
        if (mc_max < 1) mc_max = 1;
        if (mc_max > NSAMP) mc_max = NSAMP;
    }

    for (int mb = 0; mb < NSAMP; mb += mc_max) {
        int mc = NSAMP - mb; if (mc > mc_max) mc = mc_max;
        cov_kernel<<<dim3(NN, mc), 256, 0, stream>>>(cov, scal, x, y, bvec, stats, mb);
        for (int q = 0; q < CROSS / NB; ++q) {   // panels p = 0..832
            int p = q * NB;
            if (q > 0) {
                int rows = NN - p;
                int rt128 = (rows + 127) / 128;
                if (rt128 * mc >= 256) {
                    update_kernel<<<dim3(rt128, mc), 256, 0, stream>>>(cov, p);
                } else {
                    int rt64 = (rows + 63) / 64;
                    update_small_kernel<<<dim3(rt64, mc, 2), 256, 0, stream>>>(cov, p);
                }
            }
            int rb = NN - p - NB;
            int rtiles = rb / 64;                // rb is a multiple of 64
            trsmdiag_kernel<<<dim3(rtiles, mc), 128, 0, stream>>>(cov, bvec, stats, scal, mb, p);
        }
        tailsyrk_kernel<<<dim3(4, mc), 256, 0, stream>>>(cov);
        tailreduce_kernel<<<mc, 256, 0, stream>>>(cov);
        finish_kernel<<<mc, 256, 0, stream>>>(cov, bvec, stats, out, scal, mb);
    }
}

// Round 11
// 2337.633 us; speedup vs baseline: 1.1687x; 1.1687x over previous
//
#include <hip/hip_runtime.h>
#include <math.h>

#define NN 1024           // N (logical)
#define LD 1040           // padded leading dimension
#define NB 64             // panel width
#define TB 128            // tail handled by tailsyrk+finish
#define CROSS (NN - TB)   // 896: panel loop covers p < CROSS
#define NSAMP 64          // n_mc
#define TLW 4480          // per-sample factor scratch: 64*68 Tl + 64 rs + 64 sol

#define CCONST  (-0.91893853320467274f)   // -0.5*log(2*pi)
#define LOG2PI  (1.8378770664093453f)

__device__ __forceinline__ float bcastf(float v, int lane) {
    return __int_as_float(__builtin_amdgcn_readlane(__float_as_int(v), lane));
}
__device__ __forceinline__ float softplus_d(float v) {
    return (v > 20.f ? v : log1pf(expf(v))) + 1e-7f;
}
__device__ __forceinline__ float log_normal_f(float v, float mean, float s, float eps) {
    float d = v - mean;
    return -d * d / (2.f * s * s + eps) - logf(s) + CCONST;
}
__device__ __forceinline__ float log_lognormal_f(float v, float mean, float s) {
    float lv = logf(v);
    float d = lv - mean;
    return -d * d / (2.f * s * s + 1e-6f) - lv - logf(s) + CCONST;
}
__device__ __forceinline__ void fma4(float4& c, float a, const float4& b) {
    c.x = fmaf(a, b.x, c.x); c.y = fmaf(a, b.y, c.y);
    c.z = fmaf(a, b.z, c.z); c.w = fmaf(a, b.w, c.w);
}

// ---------------- per-sample scalars ----------------
__global__ void scal_kernel(const float* __restrict__ z,
    const float* qbm, const float* qbs, const float* qsm, const float* qss,
    const float* qem, const float* qes, const float* qzm, const float* qzs,
    const float* qnm, const float* qns, float* __restrict__ scal)
{
    int m = threadIdx.x;
    if (m >= NSAMP) return;
    float z0 = z[m*5+0], z1 = z[m*5+1], z2 = z[m*5+2], z3 = z[m*5+3], z4 = z[m*5+4];
    float spb = softplus_d(qbs[0]);
    float sps = softplus_d(qss[0]);
    float spe = softplus_d(qes[0]);
    float spz = softplus_d(qzs[0]);
    float spn = softplus_d(qns[0]);
    float sigma2 = expf(z0 * sps + qsm[0]);
    float beta   = z1 * spb + qbm[0];
    float eta    = expf(z2 * spe + qem[0]);
    float lsZ    = expf(z3 * spz + qzm[0]);
    float lsN    = expf(z4 * spn + qnm[0]);
    float s0 = softplus_d(sqrtf(logf(2.f)));
    float lp = log_normal_f(beta, 0.f, 1.f, 1e-5f)
             + log_lognormal_f(sigma2, 1.f, s0)
             + log_lognormal_f(eta,    1.f, s0)
             + log_lognormal_f(lsZ,    1.f, s0)
             + log_lognormal_f(lsN,    1.f, s0);
    float lq = log_normal_f(beta, qbm[0], spb, 1e-5f)
             + log_lognormal_f(sigma2, qsm[0], sps)
             + log_lognormal_f(eta,    qem[0], spe)
             + log_lognormal_f(lsZ,    qzm[0], spz)
             + log_lognormal_f(lsN,    qnm[0], spn);
    scal[m]           = sigma2;
    scal[NSAMP + m]   = eta;
    scal[2*NSAMP + m] = 1.f / lsZ;
    scal[3*NSAMP + m] = 1.f / lsN;
    scal[4*NSAMP + m] = beta;
    scal[5*NSAMP + m] = lp - lq;
}

// ---------------- covariance build (lower triangle) + bvec/stats init ----------------
__global__ __launch_bounds__(256)
void cov_kernel(float* __restrict__ cov, const float* __restrict__ scal,
                const float* __restrict__ x, const float* __restrict__ y,
                float* __restrict__ bvec, float* __restrict__ stats, int mbase)
{
    int i  = blockIdx.x;
    int ml = blockIdx.y;
    int m  = mbase + ml;
    if (threadIdx.x == 0) {
        bvec[(size_t)m * NN + i] = y[i] - scal[4*NSAMP + m];
        if (i == 0) { stats[2*m] = 0.f; stats[2*m+1] = 0.f; }
    }
    float sigma2 = scal[m];
    float eta    = scal[NSAMP + m];
    float ilZ    = scal[2*NSAMP + m];
    float ilN    = scal[3*NSAMP + m];
    float xi0 = x[2*i]   * ilZ;
    float xi1 = x[2*i+1] * ilN;
    float* row = cov + (size_t)ml * NN * LD + (size_t)i * LD;
    int j0 = threadIdx.x * 4;
    if (j0 > i) return;
    float4 xa = *(const float4*)(x + 2*j0);
    float4 xb = *(const float4*)(x + 2*j0 + 4);
    float v[4]; float d0, d1;
    d0 = xa.x*ilZ - xi0; d1 = xa.y*ilN - xi1; v[0] = eta*__expf(-0.5f*(d0*d0+d1*d1));
    d0 = xa.z*ilZ - xi0; d1 = xa.w*ilN - xi1; v[1] = eta*__expf(-0.5f*(d0*d0+d1*d1));
    d0 = xb.x*ilZ - xi0; d1 = xb.y*ilN - xi1; v[2] = eta*__expf(-0.5f*(d0*d0+d1*d1));
    d0 = xb.z*ilZ - xi0; d1 = xb.w*ilN - xi1; v[3] = eta*__expf(-0.5f*(d0*d0+d1*d1));
    #pragma unroll
    for (int q = 0; q < 4; ++q) if (j0 + q == i) v[q] += sigma2;
    if (j0 + 3 <= i) {
        float4 o; o.x = v[0]; o.y = v[1]; o.z = v[2]; o.w = v[3];
        *(float4*)(row + j0) = o;
    } else {
        #pragma unroll
        for (int q = 0; q < 4; ++q) if (j0 + q <= i) row[j0+q] = v[q];
    }
}

// ---------------- left-looking block-column update (GEMM, K = p) ----------------
__global__ __launch_bounds__(256)
void update_kernel(float* __restrict__ covb, int p)
{
    int ml = blockIdx.y;
    float* C = covb + (size_t)ml * NN * LD;
    int rowbase = p + blockIdx.x * 128;

    __shared__ __align__(16) float As[32][132];  // k-major, 128 rows
    __shared__ __align__(16) float Bs[32][68];   // k-major, 64 rows

    int tid = threadIdx.x;
    int tx = tid & 7,  ty = tid >> 3;
    int c0 = tx * 8,   r0 = ty * 4;

    float4 acc[4][2];
    #pragma unroll
    for (int r = 0; r < 4; ++r) { acc[r][0] = make_float4(0,0,0,0); acc[r][1] = make_float4(0,0,0,0); }

    for (int ks = 0; ks < p; ks += 32) {
        for (int idx = tid; idx < 128 * 8; idx += 256) {
            int ii = idx >> 3;
            int c4 = (idx & 7) << 2;
            int gr = rowbase + ii;
            float4 v = make_float4(0,0,0,0);
            if (gr < NN) v = *(const float4*)(C + (size_t)gr * LD + ks + c4);
            As[c4+0][ii] = v.x; As[c4+1][ii] = v.y;
            As[c4+2][ii] = v.z; As[c4+3][ii] = v.w;
        }
        for (int idx = tid; idx < 64 * 8; idx += 256) {
            int ii = idx >> 3;
            int c4 = (idx & 7) << 2;
            float4 v = *(const float4*)(C + (size_t)(p + ii) * LD + ks + c4);
            Bs[c4+0][ii] = v.x; Bs[c4+1][ii] = v.y;
            Bs[c4+2][ii] = v.z; Bs[c4+3][ii] = v.w;
        }
        __syncthreads();
        #pragma unroll
        for (int k = 0; k < 32; ++k) {
            float4 b0 = *(const float4*)&Bs[k][c0];
            float4 b1 = *(const float4*)&Bs[k][c0 + 4];
            float4 a0 = *(const float4*)&As[k][r0];
            float ar[4] = {a0.x, a0.y, a0.z, a0.w};
            #pragma unroll
            for (int r = 0; r < 4; ++r) {
                fma4(acc[r][0], ar[r], b0);
                fma4(acc[r][1], ar[r], b1);
            }
        }
        __syncthreads();
    }

    int jcol = p + c0;
    #pragma unroll
    for (int r = 0; r < 4; ++r) {
        int g = rowbase + r0 + r;
        if (g < NN) {
            float* cp = C + (size_t)g * LD + jcol;
            float4 u0 = *(float4*)cp;
            float4 u1 = *((float4*)cp + 1);
            u0.x -= acc[r][0].x; u0.y -= acc[r][0].y; u0.z -= acc[r][0].z; u0.w -= acc[r][0].w;
            u1.x -= acc[r][1].x; u1.y -= acc[r][1].y; u1.z -= acc[r][1].z; u1.w -= acc[r][1].w;
            *(float4*)cp = u0;
            *((float4*)cp + 1) = u1;
        }
    }
}

// ---------------- small-tile update for late panels (rt*mc starved) ----------------
__global__ __launch_bounds__(256)
void update_small_kernel(float* __restrict__ covb, int p)
{
    int ml = blockIdx.y;
    float* C = covb + (size_t)ml * NN * LD;
    int rowbase = p + blockIdx.x * 64;
    int zoff = blockIdx.z * 32;

    __shared__ __align__(16) float As[32][68];   // k-major, 64 rows
    __shared__ __align__(16) float Bs[32][36];   // k-major, 32 rows

    int tid = threadIdx.x;
    int tx = tid & 7,  ty = tid >> 3;   // 8 col-quads x 32 row-pairs
    int c0 = tx * 4,   r0 = ty * 2;

    float4 acc0 = make_float4(0,0,0,0), acc1 = make_float4(0,0,0,0);

    for (int ks = 0; ks < p; ks += 32) {
        for (int idx = tid; idx < 64 * 8; idx += 256) {
            int ii = idx >> 3;
            int c4 = (idx & 7) << 2;
            int gr = rowbase + ii;
            float4 v = make_float4(0,0,0,0);
            if (gr < NN) v = *(const float4*)(C + (size_t)gr * LD + ks + c4);
            As[c4+0][ii] = v.x; As[c4+1][ii] = v.y;
            As[c4+2][ii] = v.z; As[c4+3][ii] = v.w;
        }
        {
            int idx = tid;                      // 32*8 = 256 exactly
            int ii = idx >> 3;
            int c4 = (idx & 7) << 2;
            float4 v = *(const float4*)(C + (size_t)(p + zoff + ii) * LD + ks + c4);
            Bs[c4+0][ii] = v.x; Bs[c4+1][ii] = v.y;
            Bs[c4+2][ii] = v.z; Bs[c4+3][ii] = v.w;
        }
        __syncthreads();
        #pragma unroll
        for (int k = 0; k < 32; ++k) {
            float4 bv = *(const float4*)&Bs[k][c0];
            float2 av = *(const float2*)&As[k][r0];
            fma4(acc0, av.x, bv);
            fma4(acc1, av.y, bv);
        }
        __syncthreads();
    }

    int jcol = p + zoff + c0;
    int g0 = rowbase + r0;
    if (g0 < NN) {
        float* cp = C + (size_t)g0 * LD + jcol;
        float4 u = *(float4*)cp;
        u.x -= acc0.x; u.y -= acc0.y; u.z -= acc0.z; u.w -= acc0.w;
        *(float4*)cp = u;
    }
    if (g0 + 1 < NN) {
        float* cp = C + (size_t)(g0 + 1) * LD + jcol;
        float4 u = *(float4*)cp;
        u.x -= acc1.x; u.y -= acc1.y; u.z -= acc1.z; u.w -= acc1.w;
        *(float4*)cp = u;
    }
}

// ---------------- per-sample diag factor (once!) -> compact scratch ----------------
// one wave per sample; lane r owns row r. Writes scaled L11 rows (stride 68),
// rs (1/L_jj) and sol (forward-solve chunk) to tl_ws; accumulates stats.
// r11: de-duplicates the factor that r10's trsmdiag redid per row-block
// (FETCH was 960 blocks x 16KB of redundant diag loads = the whole 90us).
__global__ __launch_bounds__(64)
void diag_kernel(float* __restrict__ covb, const float* __restrict__ bvec,
                 float* __restrict__ tl_ws, float* __restrict__ stats,
                 int mbase, int p)
{
    int ml = blockIdx.x;
    int m  = mbase + ml;
    int r  = threadIdx.x;
    float* C = covb + (size_t)ml * NN * LD;
    float* dst = tl_ws + (size_t)ml * TLW;

    float row[NB];
    const float* src = C + (size_t)(p + r) * LD + p;
    #pragma unroll
    for (int q = 0; q < NB/4; ++q) {
        float4 v = *(const float4*)(src + 4*q);
        row[4*q+0] = v.x; row[4*q+1] = v.y; row[4*q+2] = v.z; row[4*q+3] = v.w;
    }
    float b = bvec[(size_t)m * NN + p + r];
    float quad_add = 0.f, my_d = 1.f, my_rs = 0.f, my_sol = 0.f;
    #pragma unroll
    for (int j = 0; j < NB; ++j) {
        float dj = fmaxf(bcastf(row[j], j), 1e-30f);
        float rs = rsqrtf(dj);
        if (r == j) my_d = dj;
        row[j] *= rs;                       // row[j] = L[r][j] for r>=j
        float sj = bcastf(b, j) * rs;
        quad_add = fmaf(sj, sj, quad_add);
        b = fmaf(-row[j], sj, b);
        if (r == j) { my_rs = rs; my_sol = sj; }
        #pragma unroll
        for (int c = j + 1; c < NB; ++c) {
            float s = bcastf(row[j], c);    // = L[c][j]
            row[c] = fmaf(-row[j], s, row[c]);
        }
    }
    #pragma unroll
    for (int q = 0; q < NB/4; ++q) {
        float4 v; v.x = row[4*q]; v.y = row[4*q+1]; v.z = row[4*q+2]; v.w = row[4*q+3];
        *(float4*)(dst + r * 68 + 4*q) = v;
    }
    dst[4352 + r] = my_rs;
    dst[4416 + r] = my_sol;
    float ldv = logf(my_d);
    #pragma unroll
    for (int off = 32; off > 0; off >>= 1) ldv += __shfl_down(ldv, off);
    if (r == 0) {
        stats[2*m]   += quad_add;
        stats[2*m+1] += ldv;
    }
}

// ---------------- panel TRSM from compact factor scratch ----------------
// 128 threads, 128 rows/block; grid (ceil(rb/128), mc). Stages the 17.9KB
// compact factor (contiguous, L2/L3-hot, shared by all row-blocks of a
// sample) instead of re-fetching + re-factoring the diag per block.
__global__ __launch_bounds__(128)
void trsm_kernel(float* __restrict__ covb, float* __restrict__ bvec,
                 const float* __restrict__ tl_ws, int mbase, int p)
{
    int ml = blockIdx.y;
    int m  = mbase + ml;
    float* C = covb + (size_t)ml * NN * LD;
    __shared__ __align__(16) float Tl[NB][68];
    __shared__ float rs_s[NB], sol_s[NB];
    int tid = threadIdx.x;

    const float* src = tl_ws + (size_t)ml * TLW;
    for (int f = tid; f < NB * 17; f += 128) {       // 64 rows x 17 float4
        int rr = f / 17, c4 = (f - rr * 17) * 4;
        *(float4*)&Tl[rr][c4] = *(const float4*)(src + rr * 68 + c4);
    }
    if (tid < NB) { rs_s[tid] = src[4352 + tid]; sol_s[tid] = src[4416 + tid]; }

    int r0 = p + NB + blockIdx.x * 128 + tid;
    bool have = (r0 < NN);
    float l[NB];
    if (have) {
        const float* rowp = C + (size_t)r0 * LD + p;
        #pragma unroll
        for (int q = 0; q < NB/4; ++q) {
            float4 v = *(const float4*)(rowp + 4*q);
            l[4*q] = v.x; l[4*q+1] = v.y; l[4*q+2] = v.z; l[4*q+3] = v.w;
        }
    }
    __syncthreads();

    if (!have) return;
    float* rowp = C + (size_t)r0 * LD + p;
    #pragma unroll
    for (int j = 0; j < NB; ++j) {
        float s0 = l[j], s1 = 0.f, s2 = 0.f, s3 = 0.f;
        int c = 0;
        #pragma unroll
        for (; c + 4 <= j; c += 4) {
            float4 t = *(const float4*)&Tl[j][c];
            s0 = fmaf(-l[c],   t.x, s0);
            s1 = fmaf(-l[c+1], t.y, s1);
            s2 = fmaf(-l[c+2], t.z, s2);
            s3 = fmaf(-l[c+3], t.w, s3);
        }
        #pragma unroll
        for (; c < j; ++c) s0 = fmaf(-l[c], Tl[j][c], s0);
        l[j] = ((s0 + s1) + (s2 + s3)) * rs_s[j];
    }
    #pragma unroll
    for (int q = 0; q < NB/4; ++q) {
        float4 v; v.x = l[4*q]; v.y = l[4*q+1]; v.z = l[4*q+2]; v.w = l[4*q+3];
        *(float4*)(rowp + 4*q) = v;
    }
    float b0 = 0.f, b1 = 0.f, b2 = 0.f, b3 = 0.f;
    #pragma unroll
    for (int j = 0; j < NB; j += 4) {
        b0 = fmaf(l[j],   sol_s[j],   b0);
        b1 = fmaf(l[j+1], sol_s[j+1], b1);
        b2 = fmaf(l[j+2], sol_s[j+2], b2);
        b3 = fmaf(l[j+3], sol_s[j+3], b3);
    }
    bvec[(size_t)m * NN + r0] -= ((b0 + b1) + (b2 + b3));
}

// ---------------- tail SYRK, split-K partials ----------------
__global__ __launch_bounds__(256)
void tailsyrk_kernel(float* __restrict__ covb)
{
    int ml = blockIdx.y;
    float* C = covb + (size_t)ml * NN * LD;
    int z  = blockIdx.x;
    int k0 = z * (CROSS / 4);            // 224 per segment

    __shared__ __align__(16) float As[32][132];
    int tid = threadIdx.x;
    int tx = tid & 15, ty = tid >> 4;
    int c0 = tx * 8, r0 = ty * 8;

    float4 acc[8][2];
    #pragma unroll
    for (int r = 0; r < 8; ++r) { acc[r][0] = make_float4(0,0,0,0); acc[r][1] = make_float4(0,0,0,0); }

    for (int ks = k0; ks < k0 + CROSS/4; ks += 32) {
        for (int idx = tid; idx < 128 * 8; idx += 256) {
            int ii = idx >> 3;
            int c4 = (idx & 7) << 2;
            float4 v = *(const float4*)(C + (size_t)(CROSS + ii) * LD + ks + c4);
            As[c4+0][ii] = v.x; As[c4+1][ii] = v.y;
            As[c4+2][ii] = v.z; As[c4+3][ii] = v.w;
        }
        __syncthreads();
        #pragma unroll
        for (int k = 0; k < 32; ++k) {
            float4 b0 = *(const float4*)&As[k][c0];
            float4 b1 = *(const float4*)&As[k][c0 + 4];
            float4 a0 = *(const float4*)&As[k][r0];
            float4 a1 = *(const float4*)&As[k][r0 + 4];
            float ar[8] = {a0.x, a0.y, a0.z, a0.w, a1.x, a1.y, a1.z, a1.w};
            #pragma unroll
            for (int r = 0; r < 8; ++r) {
                fma4(acc[r][0], ar[r], b0);
                fma4(acc[r][1], ar[r], b1);
            }
        }
        __syncthreads();
    }

    #pragma unroll
    for (int r = 0; r < 8; ++r) {
        float* cp = C + (size_t)(r0 + r) * LD + 512 + z * 128 + c0;
        *(float4*)cp = acc[r][0];
        *((float4*)cp + 1) = acc[r][1];
    }
}

// ---------------- reduce the 4 tail partials into C[896:,896:] ----------------
__global__ __launch_bounds__(256)
void tailreduce_kernel(float* __restrict__ covb)
{
    int ml = blockIdx.x;
    float* C = covb + (size_t)ml * NN * LD;
    int tid = threadIdx.x;
    for (int f = tid; f < 128 * 32; f += 256) {     // float4 units
        int i  = f >> 5;
        int c4 = (f & 31) << 2;
        float4 s = make_float4(0,0,0,0);
        #pragma unroll
        for (int z = 0; z < 4; ++z) {
            float4 v = *(const float4*)(C + (size_t)i * LD + 512 + z * 128 + c4);
            s.x += v.x; s.y += v.y; s.z += v.z; s.w += v.w;
        }
        float* cp = C + (size_t)(CROSS + i) * LD + CROSS + c4;
        float4 u = *(float4*)cp;
        u.x -= s.x; u.y -= s.y; u.z -= s.z; u.w -= s.w;
        *(float4*)cp = u;
    }
}

// ---------------- per-sample finish: factor last 128x128 + solve + output ----------------
__global__ __launch_bounds__(256)
void finish_kernel(float* __restrict__ covb, const float* __restrict__ bvec,
                   const float* __restrict__ stats, float* __restrict__ out,
                   const float* __restrict__ scal, int mbase)
{
    int ml = blockIdx.x;
    int m  = mbase + ml;
    float* C = covb + (size_t)ml * NN * LD;
    __shared__ __align__(16) float Tl[NB][68];
    __shared__ float rs_s[NB], sol_s[NB];
    __shared__ float bt[TB];
    __shared__ __align__(16) float Ps[NB][72];   // k-major TRSM panel (rows <= 64)
    __shared__ float s_quad, s_ld;
    int tid = threadIdx.x;

    for (int r = tid; r < TB; r += 256) bt[r] = bvec[(size_t)m * NN + CROSS + r];
    if (tid == 0) { s_quad = 0.f; s_ld = 0.f; }
    __syncthreads();

    for (int sp = 0; sp < TB/NB; ++sp) {
        int pb = CROSS + sp * NB;
        int lb = sp * NB;
        int nrem = TB - lb - NB;

        if (tid < 64) {
            int r = tid;
            float row[NB];
            const float* src = C + (size_t)(pb + r) * LD + pb;
            #pragma unroll
            for (int q = 0; q < NB/4; ++q) {
                float4 v = *(const float4*)(src + 4*q);
                row[4*q+0] = v.x; row[4*q+1] = v.y; row[4*q+2] = v.z; row[4*q+3] = v.w;
            }
            float b = bt[lb + r];
            float quad_add = 0.f, my_d = 1.f;
            #pragma unroll
            for (int j = 0; j < NB; ++j) {
                float dj = fmaxf(bcastf(row[j], j), 1e-30f);
                float rs = rsqrtf(dj);
                if (r == j) my_d = dj;
                row[j] *= rs;
                float sj = bcastf(b, j) * rs;
                quad_add = fmaf(sj, sj, quad_add);
                b = fmaf(-row[j], sj, b);
                if (r == j) { rs_s[j] = rs; sol_s[j] = sj; }
                #pragma unroll
                for (int c = j + 1; c < NB; ++c) {
                    float s = bcastf(row[j], c);
                    row[c] = fmaf(-row[j], s, row[c]);
                }
            }
            #pragma unroll
            for (int q = 0; q < NB/4; ++q) {
                float4 v; v.x = row[4*q]; v.y = row[4*q+1]; v.z = row[4*q+2]; v.w = row[4*q+3];
                *(float4*)&Tl[r][4*q] = v;
            }
            float ldv = logf(my_d);
            #pragma unroll
            for (int off = 32; off > 0; off >>= 1) ldv += __shfl_down(ldv, off);
            if (r == 0) { s_quad += quad_add; s_ld += ldv; }
        }
        __syncthreads();

        if (nrem > 0) {
            int rr = tid - 64;
            if (tid >= 64 && rr < nrem) {
                int gr = pb + NB + rr;
                const float* rowp = C + (size_t)gr * LD + pb;
                float l[NB];
                #pragma unroll
                for (int q = 0; q < NB/4; ++q) {
                    float4 v = *(const float4*)(rowp + 4*q);
                    l[4*q] = v.x; l[4*q+1] = v.y; l[4*q+2] = v.z; l[4*q+3] = v.w;
                }
                #pragma unroll
                for (int j = 0; j < NB; ++j) {
                    float s0 = l[j], s1 = 0.f, s2 = 0.f, s3 = 0.f;
                    int c = 0;
                    #pragma unroll
                    for (; c + 4 <= j; c += 4) {
                        float4 t = *(const float4*)&Tl[j][c];
                        s0 = fmaf(-l[c],   t.x, s0);
                        s1 = fmaf(-l[c+1], t.y, s1);
                        s2 = fmaf(-l[c+2], t.z, s2);
                        s3 = fmaf(-l[c+3], t.w, s3);
                    }
                    #pragma unroll
                    for (; c < j; ++c) s0 = fmaf(-l[c], Tl[j][c], s0);
                    l[j] = ((s0 + s1) + (s2 + s3)) * rs_s[j];
                }
                #pragma unroll
                for (int k = 0; k < NB; ++k) Ps[k][rr] = l[k];
                float bacc = 0.f;
                #pragma unroll
                for (int j = 0; j < NB; ++j) bacc = fmaf(l[j], sol_s[j], bacc);
                bt[lb + NB + rr] -= bacc;
            }
            __syncthreads();

            int ng = nrem >> 2;
            for (int idx = tid; idx < nrem * ng; idx += 256) {
                int i  = idx / ng;
                int j4 = (idx - i * ng) << 2;
                if (j4 > i) continue;
                float4 a = make_float4(0,0,0,0);
                #pragma unroll 8
                for (int k = 0; k < NB; ++k) {
                    float4 pj = *(const float4*)&Ps[k][j4];
                    fma4(a, Ps[k][i], pj);
                }
                float* cp = C + (size_t)(pb + NB + i) * LD + (pb + NB + j4);
                float4 u = *(float4*)cp;
                u.x -= a.x; u.y -= a.y; u.z -= a.z; u.w -= a.w;
                *(float4*)cp = u;
            }
            __syncthreads();
        }
    }

    if (tid == 0) {
        float qt = stats[2*m]   + s_quad;
        float lt = stats[2*m+1] + s_ld;
        out[m] = -0.5f * (qt + lt + (float)NN * LOG2PI) + scal[5*NSAMP + m];
    }
}

extern "C" void kernel_launch(void* const* d_in, const int* in_sizes, int n_in,
                              void* d_out, int out_size, void* d_ws, size_t ws_size,
                              hipStream_t stream)
{
    const float* x   = (const float*)d_in[0];
    const float* y   = (const float*)d_in[1];
    const float* z   = (const float*)d_in[2];
    const float* qbm = (const float*)d_in[3];
    const float* qbs = (const float*)d_in[4];
    const float* qsm = (const float*)d_in[5];
    const float* qss = (const float*)d_in[6];
    const float* qem = (const float*)d_in[7];
    const float* qes = (const float*)d_in[8];
    const float* qzm = (const float*)d_in[9];
    const float* qzs = (const float*)d_in[10];
    const float* qnm = (const float*)d_in[11];
    const float* qns = (const float*)d_in[12];
    float* out  = (float*)d_out;
    float* ws   = (float*)d_ws;

    // workspace layout (floats)
    float* scal   = ws;                                   // 384 used
    float* bvec   = ws + 1024;                            // 64*1024
    float* stats  = ws + 1024 + NSAMP*NN;                 // 128 used, 512 res
    float* tl_ws  = ws + 1024 + NSAMP*NN + 512;           // 64*4480 compact factors
    float* cov    = ws + 1024 + NSAMP*NN + 512 + NSAMP*TLW;
    size_t headF  = 1024 + (size_t)NSAMP*NN + 512 + (size_t)NSAMP*TLW;

    scal_kernel<<<1, 64, 0, stream>>>(z, qbm, qbs, qsm, qss, qem, qes, qzm, qzs, qnm, qns, scal);

    size_t availF = ws_size / 4;
    size_t perM   = (size_t)NN * LD;       // padded per-matrix footprint
    int mc_max = NSAMP;
    if (availF < headF + (size_t)NSAMP * perM) {
        size_t rem = (availF > headF) ? (availF - headF) : 0;
        mc_max = (int)(rem / perM);
        if (mc_max < 1) mc_max = 1;
        if (mc_max > NSAMP) mc_max = NSAMP;
    }

    for (int mb = 0; mb < NSAMP; mb += mc_max) {
        int mc = NSAMP - mb; if (mc > mc_max) mc = mc_max;
        cov_kernel<<<dim3(NN, mc), 256, 0, stream>>>(cov, scal, x, y, bvec, stats, mb);
        for (int q = 0; q < CROSS / NB; ++q) {   // panels p = 0..832
            int p = q * NB;
            if (q > 0) {
                int rows = NN - p;
                int rt128 = (rows + 127) / 128;
                if (rt128 * mc >= 256) {
                    update_kernel<<<dim3(rt128, mc), 256, 0, stream>>>(cov, p);
                } else {
                    int rt64 = (rows + 63) / 64;
                    update_small_kernel<<<dim3(rt64, mc, 2), 256, 0, stream>>>(cov, p);
                }
            }
            diag_kernel<<<mc, 64, 0, stream>>>(cov, bvec, tl_ws, stats, mb, p);
            int rb = NN - p - NB;
            int rtiles = (rb + 127) / 128;
            trsm_kernel<<<dim3(rtiles, mc), 128, 0, stream>>>(cov, bvec, tl_ws, mb, p);
        }
        tailsyrk_kernel<<<dim3(4, mc), 256, 0, stream>>>(cov);
        tailreduce_kernel<<<mc, 256, 0, stream>>>(cov);
        finish_kernel<<<mc, 256, 0, stream>>>(cov, bvec, stats, out, scal, mb);
    }
}